// Round 19
// baseline (144.458 us; speedup 1.0000x reference)
//
#include <hip/hip_runtime.h>
#include <stdint.h>

constexpr int kNodes    = 100000;
constexpr int kEdges    = 1600000;
constexpr int kDin      = 128;
constexpr int kK        = 256;      // concat K = [h | h_neigh]
constexpr int kDhid     = 256;
constexpr int kClasses  = 40;
constexpr int kGraphs   = 64;

constexpr int kBktShift = 8;                       // 256 nodes per bucket
constexpr int NB = (kNodes + 255) >> 8;            // 392 buckets
constexpr int kBktCap = 5120;                      // mean 4082, sigma 64 -> 16 sigma
constexpr int kChunk = 3125;                       // edges per scatter block (~8 pairs/bucket)
constexpr int kEBlocks = kEdges / kChunk;          // 512
constexpr int kSCT = 1024;                         // scatter_cvt block size
constexpr int kCvtBlocks = (kNodes * 32 + kK * kDhid) / kSCT;  // 3189 exactly

constexpr int kTPB = 5;                            // tiles/block — measured best
constexpr int kTiles = kNodes / 32;                // 3125
constexpr int kGemmBlocks = kTiles / kTPB;         // 625

typedef __attribute__((ext_vector_type(8))) short bf8_t;   // 8 x bf16 (4 VGPR)
typedef __attribute__((ext_vector_type(4))) float f4_t;    // mfma C/D
typedef __attribute__((ext_vector_type(2))) float f2_t;

__device__ inline ushort f2bf(float f) {
  uint32_t u = __float_as_uint(f);
  u += 0x7fff + ((u >> 16) & 1);          // RNE
  return (ushort)(u >> 16);
}

// ---- fp8 e4m3 helpers (HW cvt when available; manual fallback) ------------
template <bool HI>
__device__ inline f2_t fp8x2_f32(uint32_t w) {
#if __has_builtin(__builtin_amdgcn_cvt_pk_f32_fp8)
  return __builtin_amdgcn_cvt_pk_f32_fp8(w, HI);
#else
  f2_t r;
  uint32_t b0 = HI ? ((w >> 16) & 0xffu) : (w & 0xffu);
  uint32_t b1 = HI ? (w >> 24) : ((w >> 8) & 0xffu);
  auto dec = [](uint32_t b) -> float {
    uint32_t s = (b & 0x80u) << 24;
    uint32_t em = b & 0x7fu;
    float mag;
    if (em >= 0x08u) {
      uint32_t e = (em >> 3) - 7 + 127;
      mag = __uint_as_float((e << 23) | ((em & 7u) << 20));
    } else {
      mag = (float)em * 0.001953125f;   // em * 2^-9
    }
    return __uint_as_float(s | __float_as_uint(mag));
  };
  r.x = dec(b0); r.y = dec(b1);
  return r;
#endif
}

__device__ inline uint32_t f32_to_e4m3(float f) {
  uint32_t sgn = (__float_as_uint(f) >> 31) << 7;
  float mag = fabsf(f);
  uint32_t r;
  if (mag >= 0.015625f) {               // normal (>= 2^-6)
    uint32_t u = __float_as_uint(mag);
    u += 0x7FFFF + ((u >> 20) & 1);     // RNE to 3 mantissa bits
    int e = (int)(u >> 23) - 127;
    if (e > 8) r = 0x7Eu;               // clamp to 448
    else r = (uint32_t)((e + 7) << 3) | ((u >> 20) & 7u);
  } else {
    float m = mag * 512.f;              // 2^9
    int mi = (int)rintf(m);
    r = (mi > 7) ? 0x08u : (uint32_t)mi;
  }
  return r | sgn;
}

__device__ inline uint32_t pack4_e4m3(float x, float y, float z, float w) {
#if __has_builtin(__builtin_amdgcn_cvt_pk_fp8_f32)
  uint32_t p = __builtin_amdgcn_cvt_pk_fp8_f32(x, y, 0u, false);
  return __builtin_amdgcn_cvt_pk_fp8_f32(z, w, p, true);
#else
  return f32_to_e4m3(x) | (f32_to_e4m3(y) << 8) |
         (f32_to_e4m3(z) << 16) | (f32_to_e4m3(w) << 24);
#endif
}

// ---------------------------------------------------------------------------
// zero_ws: custom zeroing of gsum (16384 f32) + bktCur (512 i32 region).
// ---------------------------------------------------------------------------
__global__ void zero_ws(float* __restrict__ gsum, int* __restrict__ bktCur) {
  int t = blockIdx.x * 256 + threadIdx.x;
  if (t < kGraphs * kDhid) gsum[t] = 0.f;
  int u = t - kGraphs * kDhid;
  if (u >= 0 && u < NB) bktCur[u] = 0;
}

// ---------------------------------------------------------------------------
// scatter_cvt (1024 threads): blocks [0,scatterBlocks) do bucket scatter
// (3125 edges/block -> ~8 consecutive pair writes per bucket); remaining
// blocks do cvt h fp32 -> A16 bf16 + H8 fp8, and Wt build.
// ---------------------------------------------------------------------------
__global__ __launch_bounds__(kSCT)
void scatter_cvt(const int* __restrict__ src, const int* __restrict__ dst,
                 int* __restrict__ bktCur, uint32_t* __restrict__ pairs,
                 const float* __restrict__ h, const float* __restrict__ Ws,
                 const float* __restrict__ Wn, ushort* __restrict__ A16,
                 ushort* __restrict__ Wt, uint8_t* __restrict__ H8,
                 int scatterBlocks) {
  __shared__ int hist[NB], base[NB], cur[NB];
  if ((int)blockIdx.x < scatterBlocks) {
    for (int i = threadIdx.x; i < NB; i += kSCT) { hist[i] = 0; cur[i] = 0; }
    __syncthreads();
    int e0 = blockIdx.x * kChunk;
    int e1 = min(e0 + kChunk, kEdges);
    for (int e = e0 + threadIdx.x; e < e1; e += kSCT)
      atomicAdd(&hist[dst[e] >> kBktShift], 1);
    __syncthreads();
    for (int i = threadIdx.x; i < NB; i += kSCT)
      base[i] = hist[i] ? atomicAdd(&bktCur[i], hist[i]) : 0;
    __syncthreads();
    for (int e = e0 + threadIdx.x; e < e1; e += kSCT) {
      int d = dst[e];
      int b = d >> kBktShift;
      int p = atomicAdd(&cur[b], 1);
      pairs[(size_t)b * kBktCap + base[b] + p] = ((uint32_t)src[e] << 8) | (uint32_t)(d & 255);
    }
  } else {
    int t = ((int)blockIdx.x - scatterBlocks) * kSCT + threadIdx.x;
    const int hN = kNodes * 32;          // 3,200,000 float4-quads
    if (t < hN) {
      int n = t >> 5;
      int c4 = (t & 31) * 4;
      float4 v = *reinterpret_cast<const float4*>(h + (size_t)n * kDin + c4);
      ushort4 o;
      o.x = f2bf(v.x); o.y = f2bf(v.y); o.z = f2bf(v.z); o.w = f2bf(v.w);
      *reinterpret_cast<ushort4*>(A16 + (size_t)n * kK + c4) = o;
      *reinterpret_cast<uint32_t*>(H8 + (size_t)n * kDin + c4) =
          pack4_e4m3(v.x, v.y, v.z, v.w);
    } else {
      int u = t - hN;                    // 0 .. 65535
      int j = u & 255;
      int k = u >> 8;
      float v = (k < 128) ? Ws[(size_t)k * kDhid + j] : Wn[(size_t)(k - 128) * kDhid + j];
      Wt[(size_t)j * kK + k] = f2bf(v);
    }
  }
}

// ---------------------------------------------------------------------------
// bucket_fill: one block per bucket.  LDS degree hist -> scan -> row/rend +
// csr (gapped layout, base = b*kBktCap).
// ---------------------------------------------------------------------------
__global__ void bucket_fill(const uint32_t* __restrict__ pairs, const int* __restrict__ bktCur,
                            int* __restrict__ row, int* __restrict__ rend,
                            int* __restrict__ csr) {
  __shared__ int deg[256], scn[256], cur[256];
  int b = blockIdx.x;
  int t = threadIdx.x;
  int cnt = bktCur[b];
  int e0 = b * kBktCap;
  int nb0 = b << kBktShift;
  deg[t] = 0;
  __syncthreads();
  for (int e = t; e < cnt; e += 256)
    atomicAdd(&deg[pairs[e0 + e] & 255u], 1);
  __syncthreads();
  int d = deg[t];
  scn[t] = d;
  __syncthreads();
#pragma unroll
  for (int off = 1; off < 256; off <<= 1) {
    int u = (t >= off) ? scn[t - off] : 0;
    __syncthreads();
    scn[t] += u;
    __syncthreads();
  }
  int excl = scn[t] - d;
  cur[t] = excl;
  int n = nb0 + t;
  if (n < kNodes) { row[n] = e0 + excl; rend[n] = e0 + scn[t]; }
  __syncthreads();
  for (int e = t; e < cnt; e += 256) {
    uint32_t pr = pairs[e0 + e];
    int p = atomicAdd(&cur[pr & 255u], 1);
    csr[e0 + p] = (int)(pr >> 8);
  }
}

// ---------------------------------------------------------------------------
// aggregate8: group-per-node.  4 x 16-lane groups per wave, each group owns
// ONE node and walks its whole neighbor list (16 lanes x 8B = full 128B fp8
// row).  No cross-group reduction; direct 256B output store per group.
// ---------------------------------------------------------------------------
__global__ void aggregate8(const uint8_t* __restrict__ H8, ushort* __restrict__ A16,
                           const int* __restrict__ row, const int* __restrict__ rend,
                           const int* __restrict__ csr) {
  int wv = (blockIdx.x * 256 + threadIdx.x) >> 6;   // wave id, 25000 waves
  int lane = threadIdx.x & 63;
  int grp = lane >> 4;      // 0..3: node slot
  int sub = lane & 15;      // 0..15: 8B column chunk
  int n = wv * 4 + grp;                             // exact: 25000*4 = 100000
  int s0 = row[n], s1 = rend[n];
  float a0 = 0.f, a1 = 0.f, a2 = 0.f, a3 = 0.f, a4 = 0.f, a5 = 0.f, a6 = 0.f, a7 = 0.f;
#pragma unroll 4
  for (int i = s0; i < s1; ++i) {
    int s = csr[i];
    uint2 v = *reinterpret_cast<const uint2*>(H8 + (size_t)s * kDin + sub * 8);
    f2_t l0 = fp8x2_f32<false>(v.x), h0 = fp8x2_f32<true>(v.x);
    f2_t l1 = fp8x2_f32<false>(v.y), h1 = fp8x2_f32<true>(v.y);
    a0 += l0.x; a1 += l0.y; a2 += h0.x; a3 += h0.y;
    a4 += l1.x; a5 += l1.y; a6 += h1.x; a7 += h1.y;
  }
  float rd = 1.f / fmaxf((float)(s1 - s0), 1.f);
  uint4 o;
  o.x = (uint32_t)f2bf(a0 * rd) | ((uint32_t)f2bf(a1 * rd) << 16);
  o.y = (uint32_t)f2bf(a2 * rd) | ((uint32_t)f2bf(a3 * rd) << 16);
  o.z = (uint32_t)f2bf(a4 * rd) | ((uint32_t)f2bf(a5 * rd) << 16);
  o.w = (uint32_t)f2bf(a6 * rd) | ((uint32_t)f2bf(a7 * rd) << 16);
  *reinterpret_cast<uint4*>((char*)A16 + (size_t)n * 512 + 256 + sub * 16) = o;
}

// ---------------------------------------------------------------------------
// gemm_pool: W-stationary streaming with COUNTED-vmcnt pipeline (T4).
// Per tile: stage(t+1) -> s_waitcnt vmcnt(4) [leaves t+1's 4 loads in
// flight; guarantees tile t's 4 loads landed] -> barrier -> compute ->
// barrier.  Replaces __syncthreads' vmcnt(0) full drain, which fit the
// measured ~3.3us/tile cost across rounds 11-16.  sched_barrier(0) pins
// ds_reads below the barrier (guide rule #18).
// Round-12 lesson: never cap launch_bounds below (256,2) — spills.
// ---------------------------------------------------------------------------
__global__ __launch_bounds__(256, 2)
void gemm_pool(const ushort* __restrict__ A16, const ushort* __restrict__ Wt,
               const float* __restrict__ bias, const int* __restrict__ gid,
               float* __restrict__ gsum) {
  __shared__ ushort Abuf[2][32 * 256];   // 2 x 16 KB
  const int tid  = threadIdx.x;
  const int lane = tid & 63;
  const int wave = tid >> 6;             // col-slice: wave*64 .. +64
  const int lhi = lane >> 4;
  const int llo = lane & 15;

  bf8_t bfr[4][8];
#pragma unroll
  for (int nf = 0; nf < 4; ++nf) {
    const char* wrow = (const char*)Wt + (size_t)(wave * 64 + nf * 16 + llo) * 512 + lhi * 16;
#pragma unroll
    for (int kk = 0; kk < 8; ++kk)
      bfr[nf][kk] = *reinterpret_cast<const bf8_t*>(wrow + kk * 64);
  }
  float bv[4];
#pragma unroll
  for (int nf = 0; nf < 4; ++nf) bv[nf] = bias[wave * 64 + nf * 16 + llo];

  auto stage = [&](int buf, int tile) {
#pragma unroll
    for (int i = 0; i < 4; ++i) {
      int r = i * 8 + (tid >> 5);
      int wb = (tid & 31) * 16;
      size_t gsrc = ((size_t)tile * 32 + r) * 512 + (size_t)(wb ^ ((r & 7) << 4));
      uint32_t ldst = (uint32_t)(i * 4096 + tid * 16);
      __builtin_amdgcn_global_load_lds(
          (const __attribute__((address_space(1))) uint32_t*)((const char*)A16 + gsrc),
          (__attribute__((address_space(3))) uint32_t*)((char*)&Abuf[buf][0] + ldst),
          16, 0, 0);
    }
  };

  const int t0 = blockIdx.x * kTPB;
  stage(0, t0);

  float pooled[4] = {0.f, 0.f, 0.f, 0.f};
  int cur_g = gid[t0 * 32];

  for (int ti = 0; ti < kTPB; ++ti) {
    int tile = t0 + ti;
    if (ti + 1 < kTPB) {
      stage((ti + 1) & 1, tile + 1);
      asm volatile("s_waitcnt vmcnt(4)" ::: "memory");   // tile ti's loads done; t+1 in flight
    } else {
      asm volatile("s_waitcnt vmcnt(0)" ::: "memory");
    }
    __builtin_amdgcn_s_barrier();          // buf[ti&1] visible block-wide
    __builtin_amdgcn_sched_barrier(0);     // pin ds_reads below (rule #18)

    f4_t acc[2][4];
#pragma unroll
    for (int mf = 0; mf < 2; ++mf)
#pragma unroll
      for (int nf = 0; nf < 4; ++nf) acc[mf][nf] = (f4_t)0.f;
    const char* abase = (const char*)&Abuf[ti & 1][0];
    const int swz = (llo & 7) << 4;
#pragma unroll
    for (int kk = 0; kk < 8; ++kk) {
      int kb = kk * 64 + lhi * 16;
      bf8_t x0 = *reinterpret_cast<const bf8_t*>(abase + llo * 512 + (kb ^ swz));
      bf8_t x1 = *reinterpret_cast<const bf8_t*>(abase + (16 + llo) * 512 + (kb ^ swz));
#pragma unroll
      for (int nf = 0; nf < 4; ++nf) {
        acc[0][nf] = __builtin_amdgcn_mfma_f32_16x16x32_bf16(x0, bfr[nf][kk], acc[0][nf], 0, 0, 0);
        acc[1][nf] = __builtin_amdgcn_mfma_f32_16x16x32_bf16(x1, bfr[nf][kk], acc[1][nf], 0, 0, 0);
      }
    }

    int base = tile * 32;
    int gA = gid[base], gB = gid[base + 31];
    if (gA == gB) {
      if (gA != cur_g) {
#pragma unroll
        for (int nf = 0; nf < 4; ++nf) {
          if (pooled[nf] != 0.f)
            atomicAdd(&gsum[cur_g * kDhid + wave * 64 + nf * 16 + llo], pooled[nf]);
          pooled[nf] = 0.f;
        }
        cur_g = gA;
      }
#pragma unroll
      for (int nf = 0; nf < 4; ++nf) {
        float s = 0.f;
#pragma unroll
        for (int mf = 0; mf < 2; ++mf)
#pragma unroll
          for (int q = 0; q < 4; ++q) s += fmaxf(acc[mf][nf][q] + bv[nf], 0.f);
        pooled[nf] += s;
      }
    } else {
#pragma unroll
      for (int mf = 0; mf < 2; ++mf)
#pragma unroll
        for (int q = 0; q < 4; ++q) {
          int r = base + mf * 16 + lhi * 4 + q;
          int g = gid[r];
#pragma unroll
          for (int nf = 0; nf < 4; ++nf) {
            float v = fmaxf(acc[mf][nf][q] + bv[nf], 0.f);
            if (v != 0.f) atomicAdd(&gsum[g * kDhid + wave * 64 + nf * 16 + llo], v);
          }
        }
    }
    __builtin_amdgcn_sched_barrier(0);
    __builtin_amdgcn_s_barrier();          // all reads of buf[ti&1] done before reuse
  }

#pragma unroll
  for (int nf = 0; nf < 4; ++nf)
    if (pooled[nf] != 0.f)
      atomicAdd(&gsum[cur_g * kDhid + wave * 64 + nf * 16 + llo], pooled[nf]);
}

// ---------------------------------------------------------------------------
// head: out[g] = (gsum[g]/cnt[g]) @ Wp + bp, cnt via binary search on gid.
// ---------------------------------------------------------------------------
__global__ void head_kernel(const float* __restrict__ gsum,
                            const float* __restrict__ Wp,
                            const float* __restrict__ bp,
                            const int* __restrict__ gid,
                            float* __restrict__ out) {
  int g = blockIdx.x;
  int c = threadIdx.x;
  int lo0 = 0, hi0 = kNodes;
  while (lo0 < hi0) { int m = (lo0 + hi0) >> 1; if (gid[m] < g) lo0 = m + 1; else hi0 = m; }
  int lo1 = lo0, hi1 = kNodes;
  while (lo1 < hi1) { int m = (lo1 + hi1) >> 1; if (gid[m] < g + 1) lo1 = m + 1; else hi1 = m; }
  float rc = 1.0f / fmaxf((float)(lo1 - lo0), 1.0f);
  if (c < kClasses) {
    float acc = bp[c];
    for (int k = 0; k < kDhid; ++k)
      acc += gsum[g * kDhid + k] * rc * Wp[k * kClasses + c];
    out[g * kClasses + c] = acc;
  }
}

// ---------------------------------------------------------------------------
extern "C" void kernel_launch(void* const* d_in, const int* in_sizes, int n_in,
                              void* d_out, int out_size, void* d_ws, size_t ws_size,
                              hipStream_t stream) {
  const float* h  = (const float*)d_in[0];
  const float* Ws = (const float*)d_in[1];
  const float* Wn = (const float*)d_in[2];
  const float* b  = (const float*)d_in[3];
  const float* Wp = (const float*)d_in[4];
  const float* bp = (const float*)d_in[5];
  const int* src  = (const int*)d_in[6];
  const int* dst  = (const int*)d_in[7];
  const int* gid  = (const int*)d_in[8];
  float* out = (float*)d_out;

  char* ws = (char*)d_ws;
  const size_t a16Off    = 0;             // 100000*256*2 = 51,200,000
  const size_t wtOff     = 51249152;      // 131,072
  const size_t csrOff    = 51380224;      // 392*5120*4 = 8,028,160
  const size_t rowOff    = 59408384;      // 400,000
  const size_t rendOff   = 59808384;      // 400,000
  const size_t gsumOff   = 60208384;      // 65,536
  const size_t bktCurOff = 60273920;      // 1,568
  const size_t h8Off     = 60275712;      // 12,800,000 (fp8 gather table)
  const size_t pairsOff  = 73075712;      // 8,028,160 (non-aliased, big-ws path)
  const size_t needBig   = pairsOff + 8028160;   // 81,103,872
  ushort* A16     = (ushort*)(ws + a16Off);
  ushort* Wt      = (ushort*)(ws + wtOff);
  int* csr        = (int*)(ws + csrOff);
  int* row        = (int*)(ws + rowOff);
  int* rend       = (int*)(ws + rendOff);
  float* gsum     = (float*)(ws + gsumOff);
  int* bktCur     = (int*)(ws + bktCurOff);
  uint8_t* H8     = (uint8_t*)(ws + h8Off);
  const bool bigWs = (ws_size >= needBig);
  // small-ws fallback: pairs aliases A16 (then scatter/fill before cvt)
  uint32_t* pairs = bigWs ? (uint32_t*)(ws + pairsOff) : (uint32_t*)(ws + a16Off);

  {
    int nz = kGraphs * kDhid + NB;
    hipLaunchKernelGGL(zero_ws, dim3((nz + 255) / 256), dim3(256), 0, stream, gsum, bktCur);
  }

  if (bigWs) {
    hipLaunchKernelGGL(scatter_cvt, dim3(kEBlocks + kCvtBlocks), dim3(kSCT), 0, stream,
                       src, dst, bktCur, pairs, h, Ws, Wn, A16, Wt, H8, kEBlocks);
    hipLaunchKernelGGL(bucket_fill, dim3(NB), dim3(256), 0, stream,
                       pairs, bktCur, row, rend, csr);
  } else {
    hipLaunchKernelGGL(scatter_cvt, dim3(kEBlocks), dim3(kSCT), 0, stream,
                       src, dst, bktCur, pairs, h, Ws, Wn, A16, Wt, H8, kEBlocks);
    hipLaunchKernelGGL(bucket_fill, dim3(NB), dim3(256), 0, stream,
                       pairs, bktCur, row, rend, csr);
    hipLaunchKernelGGL(scatter_cvt, dim3(kCvtBlocks), dim3(kSCT), 0, stream,
                       src, dst, bktCur, pairs, h, Ws, Wn, A16, Wt, H8, 0);
  }

  hipLaunchKernelGGL(aggregate8, dim3(kNodes / 16), dim3(256), 0, stream,
                     H8, A16, row, rend, csr);

  hipLaunchKernelGGL(gemm_pool, dim3(kGemmBlocks), dim3(256), 0, stream,
                     A16, Wt, b, gid, gsum);
  hipLaunchKernelGGL(head_kernel, dim3(kGraphs), dim3(64), 0, stream,
                     gsum, Wp, bp, gid, out);
}

// Round 20
// 132.892 us; speedup vs baseline: 1.0870x; 1.0870x over previous
//
#include <hip/hip_runtime.h>
#include <stdint.h>

constexpr int kNodes    = 100000;
constexpr int kEdges    = 1600000;
constexpr int kDin      = 128;
constexpr int kK        = 256;      // concat K = [h | h_neigh]
constexpr int kDhid     = 256;
constexpr int kClasses  = 40;
constexpr int kGraphs   = 64;

constexpr int kBktShift = 8;                       // 256 nodes per bucket
constexpr int NB = (kNodes + 255) >> 8;            // 392 buckets
constexpr int kBktCap = 5120;                      // mean 4082, sigma 64 -> 16 sigma
constexpr int kChunk = 6250;                       // edges per scatter block (full-line writes; r13/r19: smaller chunks regress)
constexpr int kEBlocks = kEdges / kChunk;          // 256
constexpr int kSCT = 1024;                         // scatter_cvt block size
constexpr int kCvtBlocks = (kNodes * 32 + kK * kDhid) / kSCT;  // 3189 exactly

constexpr int kTPB = 5;                            // tiles/block — measured best
constexpr int kTiles = kNodes / 32;                // 3125
constexpr int kGemmBlocks = kTiles / kTPB;         // 625
constexpr int kRepl = 8;                           // gsum replicas (big-ws path)

typedef __attribute__((ext_vector_type(8))) short bf8_t;   // 8 x bf16 (4 VGPR)
typedef __attribute__((ext_vector_type(4))) float f4_t;    // mfma C/D
typedef __attribute__((ext_vector_type(2))) float f2_t;

__device__ inline ushort f2bf(float f) {
  uint32_t u = __float_as_uint(f);
  u += 0x7fff + ((u >> 16) & 1);          // RNE
  return (ushort)(u >> 16);
}

// ---- fp8 e4m3 helpers (HW cvt when available; manual fallback) ------------
template <bool HI>
__device__ inline f2_t fp8x2_f32(uint32_t w) {
#if __has_builtin(__builtin_amdgcn_cvt_pk_f32_fp8)
  return __builtin_amdgcn_cvt_pk_f32_fp8(w, HI);
#else
  f2_t r;
  uint32_t b0 = HI ? ((w >> 16) & 0xffu) : (w & 0xffu);
  uint32_t b1 = HI ? (w >> 24) : ((w >> 8) & 0xffu);
  auto dec = [](uint32_t b) -> float {
    uint32_t s = (b & 0x80u) << 24;
    uint32_t em = b & 0x7fu;
    float mag;
    if (em >= 0x08u) {
      uint32_t e = (em >> 3) - 7 + 127;
      mag = __uint_as_float((e << 23) | ((em & 7u) << 20));
    } else {
      mag = (float)em * 0.001953125f;   // em * 2^-9
    }
    return __uint_as_float(s | __float_as_uint(mag));
  };
  r.x = dec(b0); r.y = dec(b1);
  return r;
#endif
}

__device__ inline uint32_t f32_to_e4m3(float f) {
  uint32_t sgn = (__float_as_uint(f) >> 31) << 7;
  float mag = fabsf(f);
  uint32_t r;
  if (mag >= 0.015625f) {               // normal (>= 2^-6)
    uint32_t u = __float_as_uint(mag);
    u += 0x7FFFF + ((u >> 20) & 1);     // RNE to 3 mantissa bits
    int e = (int)(u >> 23) - 127;
    if (e > 8) r = 0x7Eu;               // clamp to 448
    else r = (uint32_t)((e + 7) << 3) | ((u >> 20) & 7u);
  } else {
    float m = mag * 512.f;              // 2^9
    int mi = (int)rintf(m);
    r = (mi > 7) ? 0x08u : (uint32_t)mi;
  }
  return r | sgn;
}

__device__ inline uint32_t pack4_e4m3(float x, float y, float z, float w) {
#if __has_builtin(__builtin_amdgcn_cvt_pk_fp8_f32)
  uint32_t p = __builtin_amdgcn_cvt_pk_fp8_f32(x, y, 0u, false);
  return __builtin_amdgcn_cvt_pk_fp8_f32(z, w, p, true);
#else
  return f32_to_e4m3(x) | (f32_to_e4m3(y) << 8) |
         (f32_to_e4m3(z) << 16) | (f32_to_e4m3(w) << 24);
#endif
}

// ---------------------------------------------------------------------------
// zero_bkt: zero bucket cursors (392 ints).
// ---------------------------------------------------------------------------
__global__ void zero_bkt(int* __restrict__ bktCur) {
  int t = blockIdx.x * 256 + threadIdx.x;
  if (t < NB) bktCur[t] = 0;
}

// ---------------------------------------------------------------------------
// zero_gsum: zero nrepl * 16384 floats (launched after bucket_fill so the
// big-ws path can reuse the dead pairs region for replicas).
// ---------------------------------------------------------------------------
__global__ void zero_gsum(float* __restrict__ g, int n) {
  int t = blockIdx.x * 256 + threadIdx.x;
  if (t < n) g[t] = 0.f;
}

// ---------------------------------------------------------------------------
// scatter_cvt (1024 threads): blocks [0,scatterBlocks) do bucket scatter
// (6250 edges/block -> ~16 consecutive pair writes per bucket = full lines);
// remaining blocks do cvt h fp32 -> A16 bf16 + H8 fp8, and Wt build.
// ---------------------------------------------------------------------------
__global__ __launch_bounds__(kSCT)
void scatter_cvt(const int* __restrict__ src, const int* __restrict__ dst,
                 int* __restrict__ bktCur, uint32_t* __restrict__ pairs,
                 const float* __restrict__ h, const float* __restrict__ Ws,
                 const float* __restrict__ Wn, ushort* __restrict__ A16,
                 ushort* __restrict__ Wt, uint8_t* __restrict__ H8,
                 int scatterBlocks) {
  __shared__ int hist[NB], base[NB], cur[NB];
  if ((int)blockIdx.x < scatterBlocks) {
    for (int i = threadIdx.x; i < NB; i += kSCT) { hist[i] = 0; cur[i] = 0; }
    __syncthreads();
    int e0 = blockIdx.x * kChunk;
    int e1 = min(e0 + kChunk, kEdges);
    for (int e = e0 + threadIdx.x; e < e1; e += kSCT)
      atomicAdd(&hist[dst[e] >> kBktShift], 1);
    __syncthreads();
    for (int i = threadIdx.x; i < NB; i += kSCT)
      base[i] = hist[i] ? atomicAdd(&bktCur[i], hist[i]) : 0;
    __syncthreads();
    for (int e = e0 + threadIdx.x; e < e1; e += kSCT) {
      int d = dst[e];
      int b = d >> kBktShift;
      int p = atomicAdd(&cur[b], 1);
      pairs[(size_t)b * kBktCap + base[b] + p] = ((uint32_t)src[e] << 8) | (uint32_t)(d & 255);
    }
  } else {
    int t = ((int)blockIdx.x - scatterBlocks) * kSCT + threadIdx.x;
    const int hN = kNodes * 32;          // 3,200,000 float4-quads
    if (t < hN) {
      int n = t >> 5;
      int c4 = (t & 31) * 4;
      float4 v = *reinterpret_cast<const float4*>(h + (size_t)n * kDin + c4);
      ushort4 o;
      o.x = f2bf(v.x); o.y = f2bf(v.y); o.z = f2bf(v.z); o.w = f2bf(v.w);
      *reinterpret_cast<ushort4*>(A16 + (size_t)n * kK + c4) = o;
      *reinterpret_cast<uint32_t*>(H8 + (size_t)n * kDin + c4) =
          pack4_e4m3(v.x, v.y, v.z, v.w);
    } else {
      int u = t - hN;                    // 0 .. 65535
      int j = u & 255;
      int k = u >> 8;
      float v = (k < 128) ? Ws[(size_t)k * kDhid + j] : Wn[(size_t)(k - 128) * kDhid + j];
      Wt[(size_t)j * kK + k] = f2bf(v);
    }
  }
}

// ---------------------------------------------------------------------------
// bucket_fill: one block per bucket.  LDS degree hist -> scan -> row/rend +
// csr (gapped layout, base = b*kBktCap).
// ---------------------------------------------------------------------------
__global__ void bucket_fill(const uint32_t* __restrict__ pairs, const int* __restrict__ bktCur,
                            int* __restrict__ row, int* __restrict__ rend,
                            int* __restrict__ csr) {
  __shared__ int deg[256], scn[256], cur[256];
  int b = blockIdx.x;
  int t = threadIdx.x;
  int cnt = bktCur[b];
  int e0 = b * kBktCap;
  int nb0 = b << kBktShift;
  deg[t] = 0;
  __syncthreads();
  for (int e = t; e < cnt; e += 256)
    atomicAdd(&deg[pairs[e0 + e] & 255u], 1);
  __syncthreads();
  int d = deg[t];
  scn[t] = d;
  __syncthreads();
#pragma unroll
  for (int off = 1; off < 256; off <<= 1) {
    int u = (t >= off) ? scn[t - off] : 0;
    __syncthreads();
    scn[t] += u;
    __syncthreads();
  }
  int excl = scn[t] - d;
  cur[t] = excl;
  int n = nb0 + t;
  if (n < kNodes) { row[n] = e0 + excl; rend[n] = e0 + scn[t]; }
  __syncthreads();
  for (int e = t; e < cnt; e += 256) {
    uint32_t pr = pairs[e0 + e];
    int p = atomicAdd(&cur[pr & 255u], 1);
    csr[e0 + p] = (int)(pr >> 8);
  }
}

// ---------------------------------------------------------------------------
// aggregate8: group-per-node.  4 x 16-lane groups per wave, each group owns
// ONE node and walks its whole neighbor list (16 lanes x 8B = full 128B fp8
// row).  No cross-group reduction; direct 256B output store per group.
// ---------------------------------------------------------------------------
__global__ void aggregate8(const uint8_t* __restrict__ H8, ushort* __restrict__ A16,
                           const int* __restrict__ row, const int* __restrict__ rend,
                           const int* __restrict__ csr) {
  int wv = (blockIdx.x * 256 + threadIdx.x) >> 6;   // wave id, 25000 waves
  int lane = threadIdx.x & 63;
  int grp = lane >> 4;      // 0..3: node slot
  int sub = lane & 15;      // 0..15: 8B column chunk
  int n = wv * 4 + grp;                             // exact: 25000*4 = 100000
  int s0 = row[n], s1 = rend[n];
  float a0 = 0.f, a1 = 0.f, a2 = 0.f, a3 = 0.f, a4 = 0.f, a5 = 0.f, a6 = 0.f, a7 = 0.f;
#pragma unroll 4
  for (int i = s0; i < s1; ++i) {
    int s = csr[i];
    uint2 v = *reinterpret_cast<const uint2*>(H8 + (size_t)s * kDin + sub * 8);
    f2_t l0 = fp8x2_f32<false>(v.x), h0 = fp8x2_f32<true>(v.x);
    f2_t l1 = fp8x2_f32<false>(v.y), h1 = fp8x2_f32<true>(v.y);
    a0 += l0.x; a1 += l0.y; a2 += h0.x; a3 += h0.y;
    a4 += l1.x; a5 += l1.y; a6 += h1.x; a7 += h1.y;
  }
  float rd = 1.f / fmaxf((float)(s1 - s0), 1.f);
  uint4 o;
  o.x = (uint32_t)f2bf(a0 * rd) | ((uint32_t)f2bf(a1 * rd) << 16);
  o.y = (uint32_t)f2bf(a2 * rd) | ((uint32_t)f2bf(a3 * rd) << 16);
  o.z = (uint32_t)f2bf(a4 * rd) | ((uint32_t)f2bf(a5 * rd) << 16);
  o.w = (uint32_t)f2bf(a6 * rd) | ((uint32_t)f2bf(a7 * rd) << 16);
  *reinterpret_cast<uint4*>((char*)A16 + (size_t)n * 512 + 256 + sub * 16) = o;
}

// ---------------------------------------------------------------------------
// gemm_pool: W-stationary streaming, counted-vmcnt pipeline.  ATOMIC-PRESSURE
// FIX (round-20 ablation): (1) shfl-reduce pooled across the 4 lhi groups
// (lanes ^16,^32) -> 1 atomic/col instead of 4; (2) gsum replicated kRepl x,
// block uses replica blockIdx&(nrepl-1) -> per-address conflict depth /8.
// Round-12 lesson: never cap launch_bounds below (256,2) — spills.
// ---------------------------------------------------------------------------
__global__ __launch_bounds__(256, 2)
void gemm_pool(const ushort* __restrict__ A16, const ushort* __restrict__ Wt,
               const float* __restrict__ bias, const int* __restrict__ gid,
               float* __restrict__ gsumR, int replMask) {
  __shared__ ushort Abuf[2][32 * 256];   // 2 x 16 KB
  const int tid  = threadIdx.x;
  const int lane = tid & 63;
  const int wave = tid >> 6;             // col-slice: wave*64 .. +64
  const int lhi = lane >> 4;
  const int llo = lane & 15;
  float* gout = gsumR + (size_t)(blockIdx.x & replMask) * (kGraphs * kDhid);

  bf8_t bfr[4][8];
#pragma unroll
  for (int nf = 0; nf < 4; ++nf) {
    const char* wrow = (const char*)Wt + (size_t)(wave * 64 + nf * 16 + llo) * 512 + lhi * 16;
#pragma unroll
    for (int kk = 0; kk < 8; ++kk)
      bfr[nf][kk] = *reinterpret_cast<const bf8_t*>(wrow + kk * 64);
  }
  float bv[4];
#pragma unroll
  for (int nf = 0; nf < 4; ++nf) bv[nf] = bias[wave * 64 + nf * 16 + llo];

  auto stage = [&](int buf, int tile) {
#pragma unroll
    for (int i = 0; i < 4; ++i) {
      int r = i * 8 + (tid >> 5);
      int wb = (tid & 31) * 16;
      size_t gsrc = ((size_t)tile * 32 + r) * 512 + (size_t)(wb ^ ((r & 7) << 4));
      uint32_t ldst = (uint32_t)(i * 4096 + tid * 16);
      __builtin_amdgcn_global_load_lds(
          (const __attribute__((address_space(1))) uint32_t*)((const char*)A16 + gsrc),
          (__attribute__((address_space(3))) uint32_t*)((char*)&Abuf[buf][0] + ldst),
          16, 0, 0);
    }
  };

  const int t0 = blockIdx.x * kTPB;
  stage(0, t0);

  float pooled[4] = {0.f, 0.f, 0.f, 0.f};
  int cur_g = gid[t0 * 32];

  // flush: reduce across lhi (lanes ^16,^32) then one atomic per col
  auto flushp = [&](int g) {
#pragma unroll
    for (int nf = 0; nf < 4; ++nf) {
      float v = pooled[nf];
      v += __shfl_xor(v, 16, 64);
      v += __shfl_xor(v, 32, 64);
      if (lhi == 0 && v != 0.f)
        atomicAdd(&gout[g * kDhid + wave * 64 + nf * 16 + llo], v);
      pooled[nf] = 0.f;
    }
  };

  for (int ti = 0; ti < kTPB; ++ti) {
    int tile = t0 + ti;
    if (ti + 1 < kTPB) {
      stage((ti + 1) & 1, tile + 1);
      asm volatile("s_waitcnt vmcnt(4)" ::: "memory");
    } else {
      asm volatile("s_waitcnt vmcnt(0)" ::: "memory");
    }
    __builtin_amdgcn_s_barrier();
    __builtin_amdgcn_sched_barrier(0);

    f4_t acc[2][4];
#pragma unroll
    for (int mf = 0; mf < 2; ++mf)
#pragma unroll
      for (int nf = 0; nf < 4; ++nf) acc[mf][nf] = (f4_t)0.f;
    const char* abase = (const char*)&Abuf[ti & 1][0];
    const int swz = (llo & 7) << 4;
#pragma unroll
    for (int kk = 0; kk < 8; ++kk) {
      int kb = kk * 64 + lhi * 16;
      bf8_t x0 = *reinterpret_cast<const bf8_t*>(abase + llo * 512 + (kb ^ swz));
      bf8_t x1 = *reinterpret_cast<const bf8_t*>(abase + (16 + llo) * 512 + (kb ^ swz));
#pragma unroll
      for (int nf = 0; nf < 4; ++nf) {
        acc[0][nf] = __builtin_amdgcn_mfma_f32_16x16x32_bf16(x0, bfr[nf][kk], acc[0][nf], 0, 0, 0);
        acc[1][nf] = __builtin_amdgcn_mfma_f32_16x16x32_bf16(x1, bfr[nf][kk], acc[1][nf], 0, 0, 0);
      }
    }

    int base = tile * 32;
    int gA = gid[base], gB = gid[base + 31];
    if (gA == gB) {
      if (gA != cur_g) { flushp(cur_g); cur_g = gA; }
#pragma unroll
      for (int nf = 0; nf < 4; ++nf) {
        float s = 0.f;
#pragma unroll
        for (int mf = 0; mf < 2; ++mf)
#pragma unroll
          for (int q = 0; q < 4; ++q) s += fmaxf(acc[mf][nf][q] + bv[nf], 0.f);
        pooled[nf] += s;
      }
    } else {
      // boundary tile (rare): per-element atomics into this block's replica
#pragma unroll
      for (int mf = 0; mf < 2; ++mf)
#pragma unroll
        for (int q = 0; q < 4; ++q) {
          int r = base + mf * 16 + lhi * 4 + q;
          int g = gid[r];
#pragma unroll
          for (int nf = 0; nf < 4; ++nf) {
            float v = fmaxf(acc[mf][nf][q] + bv[nf], 0.f);
            if (v != 0.f) atomicAdd(&gout[g * kDhid + wave * 64 + nf * 16 + llo], v);
          }
        }
    }
    __builtin_amdgcn_sched_barrier(0);
    __builtin_amdgcn_s_barrier();
  }
  flushp(cur_g);
}

// ---------------------------------------------------------------------------
// head: out[g] = (sum_r gsumR[r][g] / cnt[g]) @ Wp + bp.  256 threads:
// phase 1 reduces replicas into LDS, phase 2 does the 256x40 matvec.
// ---------------------------------------------------------------------------
__global__ void head_kernel(const float* __restrict__ gsumR, int nrepl,
                            const float* __restrict__ Wp,
                            const float* __restrict__ bp,
                            const int* __restrict__ gid,
                            float* __restrict__ out) {
  __shared__ float sgs[kDhid];
  int g = blockIdx.x;
  int t = threadIdx.x;
  // node count via binary search on sorted gid
  int lo0 = 0, hi0 = kNodes;
  while (lo0 < hi0) { int m = (lo0 + hi0) >> 1; if (gid[m] < g) lo0 = m + 1; else hi0 = m; }
  int lo1 = lo0, hi1 = kNodes;
  while (lo1 < hi1) { int m = (lo1 + hi1) >> 1; if (gid[m] < g + 1) lo1 = m + 1; else hi1 = m; }
  float rc = 1.0f / fmaxf((float)(lo1 - lo0), 1.0f);
  float s = 0.f;
  for (int r = 0; r < nrepl; ++r)
    s += gsumR[(size_t)r * (kGraphs * kDhid) + g * kDhid + t];
  sgs[t] = s * rc;
  __syncthreads();
  if (t < kClasses) {
    float acc = bp[t];
    for (int k = 0; k < kDhid; ++k)
      acc += sgs[k] * Wp[k * kClasses + t];
    out[g * kClasses + t] = acc;
  }
}

// ---------------------------------------------------------------------------
extern "C" void kernel_launch(void* const* d_in, const int* in_sizes, int n_in,
                              void* d_out, int out_size, void* d_ws, size_t ws_size,
                              hipStream_t stream) {
  const float* h  = (const float*)d_in[0];
  const float* Ws = (const float*)d_in[1];
  const float* Wn = (const float*)d_in[2];
  const float* b  = (const float*)d_in[3];
  const float* Wp = (const float*)d_in[4];
  const float* bp = (const float*)d_in[5];
  const int* src  = (const int*)d_in[6];
  const int* dst  = (const int*)d_in[7];
  const int* gid  = (const int*)d_in[8];
  float* out = (float*)d_out;

  char* ws = (char*)d_ws;
  const size_t a16Off    = 0;             // 100000*256*2 = 51,200,000
  const size_t wtOff     = 51249152;      // 131,072
  const size_t csrOff    = 51380224;      // 392*5120*4 = 8,028,160
  const size_t rowOff    = 59408384;      // 400,000
  const size_t rendOff   = 59808384;      // 400,000
  const size_t gsumOff   = 60208384;      // 65,536 (small-ws single replica)
  const size_t bktCurOff = 60273920;      // 1,568
  const size_t h8Off     = 60275712;      // 12,800,000 (fp8 gather table)
  const size_t pairsOff  = 73075712;      // 8,028,160 (non-aliased, big-ws path)
  const size_t needBig   = pairsOff + 8028160;   // 81,103,872 (unchanged)
  ushort* A16     = (ushort*)(ws + a16Off);
  ushort* Wt      = (ushort*)(ws + wtOff);
  int* csr        = (int*)(ws + csrOff);
  int* row        = (int*)(ws + rowOff);
  int* rend       = (int*)(ws + rendOff);
  int* bktCur     = (int*)(ws + bktCurOff);
  uint8_t* H8     = (uint8_t*)(ws + h8Off);
  const bool bigWs = (ws_size >= needBig);
  // small-ws fallback: pairs aliases A16 (then scatter/fill before cvt)
  uint32_t* pairs = bigWs ? (uint32_t*)(ws + pairsOff) : (uint32_t*)(ws + a16Off);
  // gsum replicas: big path reuses the DEAD pairs region after bucket_fill
  // (8*64KB = 512KB << 8MB); small path keeps 1 replica at gsumOff.
  const int nrepl = bigWs ? kRepl : 1;
  float* gsumR    = bigWs ? (float*)(ws + pairsOff) : (float*)(ws + gsumOff);

  hipLaunchKernelGGL(zero_bkt, dim3((NB + 255) / 256), dim3(256), 0, stream, bktCur);

  if (bigWs) {
    hipLaunchKernelGGL(scatter_cvt, dim3(kEBlocks + kCvtBlocks), dim3(kSCT), 0, stream,
                       src, dst, bktCur, pairs, h, Ws, Wn, A16, Wt, H8, kEBlocks);
    hipLaunchKernelGGL(bucket_fill, dim3(NB), dim3(256), 0, stream,
                       pairs, bktCur, row, rend, csr);
  } else {
    hipLaunchKernelGGL(scatter_cvt, dim3(kEBlocks), dim3(kSCT), 0, stream,
                       src, dst, bktCur, pairs, h, Ws, Wn, A16, Wt, H8, kEBlocks);
    hipLaunchKernelGGL(bucket_fill, dim3(NB), dim3(256), 0, stream,
                       pairs, bktCur, row, rend, csr);
    hipLaunchKernelGGL(scatter_cvt, dim3(kCvtBlocks), dim3(kSCT), 0, stream,
                       src, dst, bktCur, pairs, h, Ws, Wn, A16, Wt, H8, 0);
  }

  hipLaunchKernelGGL(aggregate8, dim3(kNodes / 16), dim3(256), 0, stream,
                     H8, A16, row, rend, csr);

  // zero the replicas AFTER fill (pairs region is dead by now on big path)
  {
    int n = nrepl * kGraphs * kDhid;
    hipLaunchKernelGGL(zero_gsum, dim3((n + 255) / 256), dim3(256), 0, stream, gsumR, n);
  }

  hipLaunchKernelGGL(gemm_pool, dim3(kGemmBlocks), dim3(256), 0, stream,
                     A16, Wt, b, gid, gsumR, nrepl - 1);
  hipLaunchKernelGGL(head_kernel, dim3(kGraphs), dim3(kDhid), 0, stream,
                     gsumR, nrepl, Wp, bp, gid, out);
}

// Round 21
// 129.998 us; speedup vs baseline: 1.1112x; 1.0223x over previous
//
#include <hip/hip_runtime.h>
#include <stdint.h>

constexpr int kNodes    = 100000;
constexpr int kEdges    = 1600000;
constexpr int kDin      = 128;
constexpr int kK        = 256;      // concat K = [h | h_neigh]
constexpr int kDhid     = 256;
constexpr int kClasses  = 40;
constexpr int kGraphs   = 64;

constexpr int kBktShift = 8;                       // 256 nodes per bucket
constexpr int NB = (kNodes + 255) >> 8;            // 392 buckets
constexpr int kBktCap = 5120;                      // mean 4082, sigma 64 -> 16 sigma
constexpr int kChunk = 6250;                       // edges per scatter block
constexpr int kEBlocks = kEdges / kChunk;          // 256
constexpr int kSCT = 1024;                         // scatter_cvt block size
constexpr int kCvtBlocks = (kNodes * 32 + kK * kDhid) / kSCT;  // 3189 exactly

constexpr int kTPB = 5;                            // tiles/block — measured best
constexpr int kTiles = kNodes / 32;                // 3125
constexpr int kGemmBlocks = kTiles / kTPB;         // 625
constexpr int kRepl = 8;                           // gsum replicas (big-ws path)

typedef __attribute__((ext_vector_type(8))) short bf8_t;   // 8 x bf16 (4 VGPR)
typedef __attribute__((ext_vector_type(4))) float f4_t;    // mfma C/D
typedef __attribute__((ext_vector_type(2))) float f2_t;

__device__ inline ushort f2bf(float f) {
  uint32_t u = __float_as_uint(f);
  u += 0x7fff + ((u >> 16) & 1);          // RNE
  return (ushort)(u >> 16);
}

// ---- fp8 e4m3 helpers (HW cvt when available; manual fallback) ------------
template <bool HI>
__device__ inline f2_t fp8x2_f32(uint32_t w) {
#if __has_builtin(__builtin_amdgcn_cvt_pk_f32_fp8)
  return __builtin_amdgcn_cvt_pk_f32_fp8(w, HI);
#else
  f2_t r;
  uint32_t b0 = HI ? ((w >> 16) & 0xffu) : (w & 0xffu);
  uint32_t b1 = HI ? (w >> 24) : ((w >> 8) & 0xffu);
  auto dec = [](uint32_t b) -> float {
    uint32_t s = (b & 0x80u) << 24;
    uint32_t em = b & 0x7fu;
    float mag;
    if (em >= 0x08u) {
      uint32_t e = (em >> 3) - 7 + 127;
      mag = __uint_as_float((e << 23) | ((em & 7u) << 20));
    } else {
      mag = (float)em * 0.001953125f;   // em * 2^-9
    }
    return __uint_as_float(s | __float_as_uint(mag));
  };
  r.x = dec(b0); r.y = dec(b1);
  return r;
#endif
}

__device__ inline uint32_t f32_to_e4m3(float f) {
  uint32_t sgn = (__float_as_uint(f) >> 31) << 7;
  float mag = fabsf(f);
  uint32_t r;
  if (mag >= 0.015625f) {               // normal (>= 2^-6)
    uint32_t u = __float_as_uint(mag);
    u += 0x7FFFF + ((u >> 20) & 1);     // RNE to 3 mantissa bits
    int e = (int)(u >> 23) - 127;
    if (e > 8) r = 0x7Eu;               // clamp to 448
    else r = (uint32_t)((e + 7) << 3) | ((u >> 20) & 7u);
  } else {
    float m = mag * 512.f;              // 2^9
    int mi = (int)rintf(m);
    r = (mi > 7) ? 0x08u : (uint32_t)mi;
  }
  return r | sgn;
}

__device__ inline uint32_t pack4_e4m3(float x, float y, float z, float w) {
#if __has_builtin(__builtin_amdgcn_cvt_pk_fp8_f32)
  uint32_t p = __builtin_amdgcn_cvt_pk_fp8_f32(x, y, 0u, false);
  return __builtin_amdgcn_cvt_pk_fp8_f32(z, w, p, true);
#else
  return f32_to_e4m3(x) | (f32_to_e4m3(y) << 8) |
         (f32_to_e4m3(z) << 16) | (f32_to_e4m3(w) << 24);
#endif
}

// ---------------------------------------------------------------------------
// zero_bkt / zero_gsum
// ---------------------------------------------------------------------------
__global__ void zero_bkt(int* __restrict__ bktCur) {
  int t = blockIdx.x * 256 + threadIdx.x;
  if (t < NB) bktCur[t] = 0;
}
__global__ void zero_gsum(float* __restrict__ g, int n) {
  int t = blockIdx.x * 256 + threadIdx.x;
  if (t < n) g[t] = 0.f;
}

// ---------------------------------------------------------------------------
// scatter_cvt (1024 threads): scatter branch now does an IN-LDS COUNTING
// SORT before writing pairs: hist -> 512-wide scan (local offsets + global
// reservation) -> scatter into LDS (val/addrs; addrs consecutive within a
// bucket segment) -> linear copy-out (wave's 64 stores span ~5 lines, not
// 64).  Fixes round-20's 8.6x pair-write amplification (55MB vs 6.4MB).
// cvt branch unchanged: h fp32 -> A16 bf16 + H8 fp8, Wt build.
// LDS 56KB/block -> 2 blocks/CU for both branches.
// ---------------------------------------------------------------------------
__global__ __launch_bounds__(kSCT)
void scatter_cvt(const int* __restrict__ src, const int* __restrict__ dst,
                 int* __restrict__ bktCur, uint32_t* __restrict__ pairs,
                 const float* __restrict__ h, const float* __restrict__ Ws,
                 const float* __restrict__ Wn, ushort* __restrict__ A16,
                 ushort* __restrict__ Wt, uint8_t* __restrict__ H8,
                 int scatterBlocks) {
  __shared__ uint32_t val[kChunk];      // 25,000 B
  __shared__ int addrs[kChunk];         // 25,000 B
  __shared__ int hist[NB], cur[NB], lofs[NB], segoff[NB];
  __shared__ int s[512];
  const int t = threadIdx.x;
  if ((int)blockIdx.x < scatterBlocks) {
    for (int i = t; i < NB; i += kSCT) { hist[i] = 0; cur[i] = 0; }
    __syncthreads();
    int e0 = blockIdx.x * kChunk;
    int e1 = min(e0 + kChunk, kEdges);
    int cnt = e1 - e0;
    for (int e = e0 + t; e < e1; e += kSCT)
      atomicAdd(&hist[dst[e] >> kBktShift], 1);
    __syncthreads();
    // 512-wide inclusive scan of hist
    if (t < 512) s[t] = (t < NB) ? hist[t] : 0;
    __syncthreads();
    for (int off = 1; off < 512; off <<= 1) {
      int u = 0;
      if (t < 512 && t >= off) u = s[t - off];
      __syncthreads();
      if (t < 512) s[t] += u;
      __syncthreads();
    }
    if (t < NB) {
      int excl = s[t] - hist[t];
      lofs[t] = excl;
      int bs = hist[t] ? atomicAdd(&bktCur[t], hist[t]) : 0;
      segoff[t] = t * kBktCap + bs - excl;
    }
    __syncthreads();
    // scatter into LDS staging (bucket-ordered)
    for (int e = e0 + t; e < e1; e += kSCT) {
      int d = dst[e];
      int b = d >> kBktShift;
      int p = atomicAdd(&cur[b], 1);
      int slot = lofs[b] + p;
      val[slot] = ((uint32_t)src[e] << 8) | (uint32_t)(d & 255);
      addrs[slot] = segoff[b] + slot;
    }
    __syncthreads();
    // linear copy-out: consecutive slots -> consecutive global addresses
    for (int i = t; i < cnt; i += kSCT)
      pairs[addrs[i]] = val[i];
  } else {
    int tt = ((int)blockIdx.x - scatterBlocks) * kSCT + t;
    const int hN = kNodes * 32;          // 3,200,000 float4-quads
    if (tt < hN) {
      int n = tt >> 5;
      int c4 = (tt & 31) * 4;
      float4 v = *reinterpret_cast<const float4*>(h + (size_t)n * kDin + c4);
      ushort4 o;
      o.x = f2bf(v.x); o.y = f2bf(v.y); o.z = f2bf(v.z); o.w = f2bf(v.w);
      *reinterpret_cast<ushort4*>(A16 + (size_t)n * kK + c4) = o;
      *reinterpret_cast<uint32_t*>(H8 + (size_t)n * kDin + c4) =
          pack4_e4m3(v.x, v.y, v.z, v.w);
    } else {
      int u = tt - hN;                   // 0 .. 65535
      int j = u & 255;
      int k = u >> 8;
      float v = (k < 128) ? Ws[(size_t)k * kDhid + j] : Wn[(size_t)(k - 128) * kDhid + j];
      Wt[(size_t)j * kK + k] = f2bf(v);
    }
  }
}

// ---------------------------------------------------------------------------
// bucket_fill: one block per bucket.  LDS degree hist -> scan -> row/rend +
// csr (gapped layout, base = b*kBktCap).
// ---------------------------------------------------------------------------
__global__ void bucket_fill(const uint32_t* __restrict__ pairs, const int* __restrict__ bktCur,
                            int* __restrict__ row, int* __restrict__ rend,
                            int* __restrict__ csr) {
  __shared__ int deg[256], scn[256], cur[256];
  int b = blockIdx.x;
  int t = threadIdx.x;
  int cnt = bktCur[b];
  int e0 = b * kBktCap;
  int nb0 = b << kBktShift;
  deg[t] = 0;
  __syncthreads();
  for (int e = t; e < cnt; e += 256)
    atomicAdd(&deg[pairs[e0 + e] & 255u], 1);
  __syncthreads();
  int d = deg[t];
  scn[t] = d;
  __syncthreads();
#pragma unroll
  for (int off = 1; off < 256; off <<= 1) {
    int u = (t >= off) ? scn[t - off] : 0;
    __syncthreads();
    scn[t] += u;
    __syncthreads();
  }
  int excl = scn[t] - d;
  cur[t] = excl;
  int n = nb0 + t;
  if (n < kNodes) { row[n] = e0 + excl; rend[n] = e0 + scn[t]; }
  __syncthreads();
  for (int e = t; e < cnt; e += 256) {
    uint32_t pr = pairs[e0 + e];
    int p = atomicAdd(&cur[pr & 255u], 1);
    csr[e0 + p] = (int)(pr >> 8);
  }
}

// ---------------------------------------------------------------------------
// aggregate8: group-per-node.  4 x 16-lane groups per wave, each group owns
// ONE node and walks its whole neighbor list (16 lanes x 8B = full 128B fp8
// row).  No cross-group reduction; direct 256B output store per group.
// ---------------------------------------------------------------------------
__global__ void aggregate8(const uint8_t* __restrict__ H8, ushort* __restrict__ A16,
                           const int* __restrict__ row, const int* __restrict__ rend,
                           const int* __restrict__ csr) {
  int wv = (blockIdx.x * 256 + threadIdx.x) >> 6;   // wave id, 25000 waves
  int lane = threadIdx.x & 63;
  int grp = lane >> 4;      // 0..3: node slot
  int sub = lane & 15;      // 0..15: 8B column chunk
  int n = wv * 4 + grp;                             // exact: 25000*4 = 100000
  int s0 = row[n], s1 = rend[n];
  float a0 = 0.f, a1 = 0.f, a2 = 0.f, a3 = 0.f, a4 = 0.f, a5 = 0.f, a6 = 0.f, a7 = 0.f;
#pragma unroll 4
  for (int i = s0; i < s1; ++i) {
    int s = csr[i];
    uint2 v = *reinterpret_cast<const uint2*>(H8 + (size_t)s * kDin + sub * 8);
    f2_t l0 = fp8x2_f32<false>(v.x), h0 = fp8x2_f32<true>(v.x);
    f2_t l1 = fp8x2_f32<false>(v.y), h1 = fp8x2_f32<true>(v.y);
    a0 += l0.x; a1 += l0.y; a2 += h0.x; a3 += h0.y;
    a4 += l1.x; a5 += l1.y; a6 += h1.x; a7 += h1.y;
  }
  float rd = 1.f / fmaxf((float)(s1 - s0), 1.f);
  uint4 o;
  o.x = (uint32_t)f2bf(a0 * rd) | ((uint32_t)f2bf(a1 * rd) << 16);
  o.y = (uint32_t)f2bf(a2 * rd) | ((uint32_t)f2bf(a3 * rd) << 16);
  o.z = (uint32_t)f2bf(a4 * rd) | ((uint32_t)f2bf(a5 * rd) << 16);
  o.w = (uint32_t)f2bf(a6 * rd) | ((uint32_t)f2bf(a7 * rd) << 16);
  *reinterpret_cast<uint4*>((char*)A16 + (size_t)n * 512 + 256 + sub * 16) = o;
}

// ---------------------------------------------------------------------------
// gemm_pool: W-stationary streaming, counted-vmcnt pipeline, reduced-atomic
// pooling (shfl across lhi groups -> 1 atomic/col; 8 gsum replicas).
// Round-12 lesson: never cap launch_bounds below (256,2) — spills.
// ---------------------------------------------------------------------------
__global__ __launch_bounds__(256, 2)
void gemm_pool(const ushort* __restrict__ A16, const ushort* __restrict__ Wt,
               const float* __restrict__ bias, const int* __restrict__ gid,
               float* __restrict__ gsumR, int replMask) {
  __shared__ ushort Abuf[2][32 * 256];   // 2 x 16 KB
  const int tid  = threadIdx.x;
  const int lane = tid & 63;
  const int wave = tid >> 6;             // col-slice: wave*64 .. +64
  const int lhi = lane >> 4;
  const int llo = lane & 15;
  float* gout = gsumR + (size_t)(blockIdx.x & replMask) * (kGraphs * kDhid);

  bf8_t bfr[4][8];
#pragma unroll
  for (int nf = 0; nf < 4; ++nf) {
    const char* wrow = (const char*)Wt + (size_t)(wave * 64 + nf * 16 + llo) * 512 + lhi * 16;
#pragma unroll
    for (int kk = 0; kk < 8; ++kk)
      bfr[nf][kk] = *reinterpret_cast<const bf8_t*>(wrow + kk * 64);
  }
  float bv[4];
#pragma unroll
  for (int nf = 0; nf < 4; ++nf) bv[nf] = bias[wave * 64 + nf * 16 + llo];

  auto stage = [&](int buf, int tile) {
#pragma unroll
    for (int i = 0; i < 4; ++i) {
      int r = i * 8 + (tid >> 5);
      int wb = (tid & 31) * 16;
      size_t gsrc = ((size_t)tile * 32 + r) * 512 + (size_t)(wb ^ ((r & 7) << 4));
      uint32_t ldst = (uint32_t)(i * 4096 + tid * 16);
      __builtin_amdgcn_global_load_lds(
          (const __attribute__((address_space(1))) uint32_t*)((const char*)A16 + gsrc),
          (__attribute__((address_space(3))) uint32_t*)((char*)&Abuf[buf][0] + ldst),
          16, 0, 0);
    }
  };

  const int t0 = blockIdx.x * kTPB;
  stage(0, t0);

  float pooled[4] = {0.f, 0.f, 0.f, 0.f};
  int cur_g = gid[t0 * 32];

  auto flushp = [&](int g) {
#pragma unroll
    for (int nf = 0; nf < 4; ++nf) {
      float v = pooled[nf];
      v += __shfl_xor(v, 16, 64);
      v += __shfl_xor(v, 32, 64);
      if (lhi == 0 && v != 0.f)
        atomicAdd(&gout[g * kDhid + wave * 64 + nf * 16 + llo], v);
      pooled[nf] = 0.f;
    }
  };

  for (int ti = 0; ti < kTPB; ++ti) {
    int tile = t0 + ti;
    if (ti + 1 < kTPB) {
      stage((ti + 1) & 1, tile + 1);
      asm volatile("s_waitcnt vmcnt(4)" ::: "memory");
    } else {
      asm volatile("s_waitcnt vmcnt(0)" ::: "memory");
    }
    __builtin_amdgcn_s_barrier();
    __builtin_amdgcn_sched_barrier(0);

    f4_t acc[2][4];
#pragma unroll
    for (int mf = 0; mf < 2; ++mf)
#pragma unroll
      for (int nf = 0; nf < 4; ++nf) acc[mf][nf] = (f4_t)0.f;
    const char* abase = (const char*)&Abuf[ti & 1][0];
    const int swz = (llo & 7) << 4;
#pragma unroll
    for (int kk = 0; kk < 8; ++kk) {
      int kb = kk * 64 + lhi * 16;
      bf8_t x0 = *reinterpret_cast<const bf8_t*>(abase + llo * 512 + (kb ^ swz));
      bf8_t x1 = *reinterpret_cast<const bf8_t*>(abase + (16 + llo) * 512 + (kb ^ swz));
#pragma unroll
      for (int nf = 0; nf < 4; ++nf) {
        acc[0][nf] = __builtin_amdgcn_mfma_f32_16x16x32_bf16(x0, bfr[nf][kk], acc[0][nf], 0, 0, 0);
        acc[1][nf] = __builtin_amdgcn_mfma_f32_16x16x32_bf16(x1, bfr[nf][kk], acc[1][nf], 0, 0, 0);
      }
    }

    int base = tile * 32;
    int gA = gid[base], gB = gid[base + 31];
    if (gA == gB) {
      if (gA != cur_g) { flushp(cur_g); cur_g = gA; }
#pragma unroll
      for (int nf = 0; nf < 4; ++nf) {
        float s = 0.f;
#pragma unroll
        for (int mf = 0; mf < 2; ++mf)
#pragma unroll
          for (int q = 0; q < 4; ++q) s += fmaxf(acc[mf][nf][q] + bv[nf], 0.f);
        pooled[nf] += s;
      }
    } else {
#pragma unroll
      for (int mf = 0; mf < 2; ++mf)
#pragma unroll
        for (int q = 0; q < 4; ++q) {
          int r = base + mf * 16 + lhi * 4 + q;
          int g = gid[r];
#pragma unroll
          for (int nf = 0; nf < 4; ++nf) {
            float v = fmaxf(acc[mf][nf][q] + bv[nf], 0.f);
            if (v != 0.f) atomicAdd(&gout[g * kDhid + wave * 64 + nf * 16 + llo], v);
          }
        }
    }
    __builtin_amdgcn_sched_barrier(0);
    __builtin_amdgcn_s_barrier();
  }
  flushp(cur_g);
}

// ---------------------------------------------------------------------------
// head: out[g] = (sum_r gsumR[r][g] / cnt[g]) @ Wp + bp.
// ---------------------------------------------------------------------------
__global__ void head_kernel(const float* __restrict__ gsumR, int nrepl,
                            const float* __restrict__ Wp,
                            const float* __restrict__ bp,
                            const int* __restrict__ gid,
                            float* __restrict__ out) {
  __shared__ float sgs[kDhid];
  int g = blockIdx.x;
  int t = threadIdx.x;
  int lo0 = 0, hi0 = kNodes;
  while (lo0 < hi0) { int m = (lo0 + hi0) >> 1; if (gid[m] < g) lo0 = m + 1; else hi0 = m; }
  int lo1 = lo0, hi1 = kNodes;
  while (lo1 < hi1) { int m = (lo1 + hi1) >> 1; if (gid[m] < g + 1) lo1 = m + 1; else hi1 = m; }
  float rc = 1.0f / fmaxf((float)(lo1 - lo0), 1.0f);
  float s = 0.f;
  for (int r = 0; r < nrepl; ++r)
    s += gsumR[(size_t)r * (kGraphs * kDhid) + g * kDhid + t];
  sgs[t] = s * rc;
  __syncthreads();
  if (t < kClasses) {
    float acc = bp[t];
    for (int k = 0; k < kDhid; ++k)
      acc += sgs[k] * Wp[k * kClasses + t];
    out[g * kClasses + t] = acc;
  }
}

// ---------------------------------------------------------------------------
extern "C" void kernel_launch(void* const* d_in, const int* in_sizes, int n_in,
                              void* d_out, int out_size, void* d_ws, size_t ws_size,
                              hipStream_t stream) {
  const float* h  = (const float*)d_in[0];
  const float* Ws = (const float*)d_in[1];
  const float* Wn = (const float*)d_in[2];
  const float* b  = (const float*)d_in[3];
  const float* Wp = (const float*)d_in[4];
  const float* bp = (const float*)d_in[5];
  const int* src  = (const int*)d_in[6];
  const int* dst  = (const int*)d_in[7];
  const int* gid  = (const int*)d_in[8];
  float* out = (float*)d_out;

  char* ws = (char*)d_ws;
  const size_t a16Off    = 0;             // 100000*256*2 = 51,200,000
  const size_t wtOff     = 51249152;      // 131,072
  const size_t csrOff    = 51380224;      // 392*5120*4 = 8,028,160
  const size_t rowOff    = 59408384;      // 400,000
  const size_t rendOff   = 59808384;      // 400,000
  const size_t gsumOff   = 60208384;      // 65,536 (small-ws single replica)
  const size_t bktCurOff = 60273920;      // 1,568
  const size_t h8Off     = 60275712;      // 12,800,000 (fp8 gather table)
  const size_t pairsOff  = 73075712;      // 8,028,160 (non-aliased, big-ws path)
  const size_t needBig   = pairsOff + 8028160;   // 81,103,872
  ushort* A16     = (ushort*)(ws + a16Off);
  ushort* Wt      = (ushort*)(ws + wtOff);
  int* csr        = (int*)(ws + csrOff);
  int* row        = (int*)(ws + rowOff);
  int* rend       = (int*)(ws + rendOff);
  int* bktCur     = (int*)(ws + bktCurOff);
  uint8_t* H8     = (uint8_t*)(ws + h8Off);
  const bool bigWs = (ws_size >= needBig);
  uint32_t* pairs = bigWs ? (uint32_t*)(ws + pairsOff) : (uint32_t*)(ws + a16Off);
  const int nrepl = bigWs ? kRepl : 1;
  float* gsumR    = bigWs ? (float*)(ws + pairsOff) : (float*)(ws + gsumOff);

  hipLaunchKernelGGL(zero_bkt, dim3((NB + 255) / 256), dim3(256), 0, stream, bktCur);

  if (bigWs) {
    hipLaunchKernelGGL(scatter_cvt, dim3(kEBlocks + kCvtBlocks), dim3(kSCT), 0, stream,
                       src, dst, bktCur, pairs, h, Ws, Wn, A16, Wt, H8, kEBlocks);
    hipLaunchKernelGGL(bucket_fill, dim3(NB), dim3(256), 0, stream,
                       pairs, bktCur, row, rend, csr);
  } else {
    hipLaunchKernelGGL(scatter_cvt, dim3(kEBlocks), dim3(kSCT), 0, stream,
                       src, dst, bktCur, pairs, h, Ws, Wn, A16, Wt, H8, kEBlocks);
    hipLaunchKernelGGL(bucket_fill, dim3(NB), dim3(256), 0, stream,
                       pairs, bktCur, row, rend, csr);
    hipLaunchKernelGGL(scatter_cvt, dim3(kCvtBlocks), dim3(kSCT), 0, stream,
                       src, dst, bktCur, pairs, h, Ws, Wn, A16, Wt, H8, 0);
  }

  hipLaunchKernelGGL(aggregate8, dim3(kNodes / 16), dim3(256), 0, stream,
                     H8, A16, row, rend, csr);

  // zero the replicas AFTER fill (pairs region is dead by now on big path)
  {
    int n = nrepl * kGraphs * kDhid;
    hipLaunchKernelGGL(zero_gsum, dim3((n + 255) / 256), dim3(256), 0, stream, gsumR, n);
  }

  hipLaunchKernelGGL(gemm_pool, dim3(kGemmBlocks), dim3(256), 0, stream,
                     A16, Wt, b, gid, gsumR, nrepl - 1);
  hipLaunchKernelGGL(head_kernel, dim3(kGraphs), dim3(kDhid), 0, stream,
                     gsumR, nrepl, Wp, bp, gid, out);
}

// Round 22
// 128.597 us; speedup vs baseline: 1.1233x; 1.0109x over previous
//
#include <hip/hip_runtime.h>
#include <stdint.h>

constexpr int kNodes    = 100000;
constexpr int kEdges    = 1600000;
constexpr int kDin      = 128;
constexpr int kK        = 256;      // concat K = [h | h_neigh]
constexpr int kDhid     = 256;
constexpr int kClasses  = 40;
constexpr int kGraphs   = 64;

constexpr int kBktShift = 8;                       // 256 nodes per bucket
constexpr int NB = (kNodes + 255) >> 8;            // 392 buckets
constexpr int kBktCap = 5120;                      // mean 4082, sigma 64 -> 16 sigma
constexpr int kChunk = 6250;                       // edges per scatter block
constexpr int kEBlocks = kEdges / kChunk;          // 256
constexpr int kSCT = 1024;                         // scatter_cvt block size
constexpr int kCvtBlocks = (kNodes * 32 + kK * kDhid) / kSCT;  // 3189 exactly

constexpr int kTPB = 5;                            // tiles/block — measured best
constexpr int kTiles = kNodes / 32;                // 3125
constexpr int kGemmBlocks = kTiles / kTPB;         // 625
constexpr int kRepl = 8;                           // gsum replicas (big-ws path)
constexpr int kAggBlocks = kNodes / 16;            // 6250

typedef __attribute__((ext_vector_type(8))) short bf8_t;   // 8 x bf16 (4 VGPR)
typedef __attribute__((ext_vector_type(4))) float f4_t;    // mfma C/D
typedef __attribute__((ext_vector_type(2))) float f2_t;

__device__ inline ushort f2bf(float f) {
  uint32_t u = __float_as_uint(f);
  u += 0x7fff + ((u >> 16) & 1);          // RNE
  return (ushort)(u >> 16);
}

// ---- fp8 e4m3 helpers (HW cvt when available; manual fallback) ------------
template <bool HI>
__device__ inline f2_t fp8x2_f32(uint32_t w) {
#if __has_builtin(__builtin_amdgcn_cvt_pk_f32_fp8)
  return __builtin_amdgcn_cvt_pk_f32_fp8(w, HI);
#else
  f2_t r;
  uint32_t b0 = HI ? ((w >> 16) & 0xffu) : (w & 0xffu);
  uint32_t b1 = HI ? (w >> 24) : ((w >> 8) & 0xffu);
  auto dec = [](uint32_t b) -> float {
    uint32_t s = (b & 0x80u) << 24;
    uint32_t em = b & 0x7fu;
    float mag;
    if (em >= 0x08u) {
      uint32_t e = (em >> 3) - 7 + 127;
      mag = __uint_as_float((e << 23) | ((em & 7u) << 20));
    } else {
      mag = (float)em * 0.001953125f;   // em * 2^-9
    }
    return __uint_as_float(s | __float_as_uint(mag));
  };
  r.x = dec(b0); r.y = dec(b1);
  return r;
#endif
}

__device__ inline uint32_t f32_to_e4m3(float f) {
  uint32_t sgn = (__float_as_uint(f) >> 31) << 7;
  float mag = fabsf(f);
  uint32_t r;
  if (mag >= 0.015625f) {               // normal (>= 2^-6)
    uint32_t u = __float_as_uint(mag);
    u += 0x7FFFF + ((u >> 20) & 1);     // RNE to 3 mantissa bits
    int e = (int)(u >> 23) - 127;
    if (e > 8) r = 0x7Eu;               // clamp to 448
    else r = (uint32_t)((e + 7) << 3) | ((u >> 20) & 7u);
  } else {
    float m = mag * 512.f;              // 2^9
    int mi = (int)rintf(m);
    r = (mi > 7) ? 0x08u : (uint32_t)mi;
  }
  return r | sgn;
}

__device__ inline uint32_t pack4_e4m3(float x, float y, float z, float w) {
#if __has_builtin(__builtin_amdgcn_cvt_pk_fp8_f32)
  uint32_t p = __builtin_amdgcn_cvt_pk_fp8_f32(x, y, 0u, false);
  return __builtin_amdgcn_cvt_pk_fp8_f32(z, w, p, true);
#else
  return f32_to_e4m3(x) | (f32_to_e4m3(y) << 8) |
         (f32_to_e4m3(z) << 16) | (f32_to_e4m3(w) << 24);
#endif
}

// ---------------------------------------------------------------------------
// zero_bkt: zero bucket cursors (must precede scatter_cvt; cross-block dep).
// ---------------------------------------------------------------------------
__global__ void zero_bkt(int* __restrict__ bktCur) {
  int t = blockIdx.x * 256 + threadIdx.x;
  if (t < NB) bktCur[t] = 0;
}

// ---------------------------------------------------------------------------
// scatter_cvt (1024 threads): scatter branch does an in-LDS counting sort
// before writing pairs (hist -> scan -> LDS staging -> linear copy-out;
// fixes the 8.6x pair-write amplification).  cvt branch: h fp32 -> A16 bf16
// + H8 fp8, Wt build.  LDS 56KB/block -> 2 blocks/CU.
// ---------------------------------------------------------------------------
__global__ __launch_bounds__(kSCT)
void scatter_cvt(const int* __restrict__ src, const int* __restrict__ dst,
                 int* __restrict__ bktCur, uint32_t* __restrict__ pairs,
                 const float* __restrict__ h, const float* __restrict__ Ws,
                 const float* __restrict__ Wn, ushort* __restrict__ A16,
                 ushort* __restrict__ Wt, uint8_t* __restrict__ H8,
                 int scatterBlocks) {
  __shared__ uint32_t val[kChunk];      // 25,000 B
  __shared__ int addrs[kChunk];         // 25,000 B
  __shared__ int hist[NB], cur[NB], lofs[NB], segoff[NB];
  __shared__ int s[512];
  const int t = threadIdx.x;
  if ((int)blockIdx.x < scatterBlocks) {
    for (int i = t; i < NB; i += kSCT) { hist[i] = 0; cur[i] = 0; }
    __syncthreads();
    int e0 = blockIdx.x * kChunk;
    int e1 = min(e0 + kChunk, kEdges);
    int cnt = e1 - e0;
    for (int e = e0 + t; e < e1; e += kSCT)
      atomicAdd(&hist[dst[e] >> kBktShift], 1);
    __syncthreads();
    if (t < 512) s[t] = (t < NB) ? hist[t] : 0;
    __syncthreads();
    for (int off = 1; off < 512; off <<= 1) {
      int u = 0;
      if (t < 512 && t >= off) u = s[t - off];
      __syncthreads();
      if (t < 512) s[t] += u;
      __syncthreads();
    }
    if (t < NB) {
      int excl = s[t] - hist[t];
      lofs[t] = excl;
      int bs = hist[t] ? atomicAdd(&bktCur[t], hist[t]) : 0;
      segoff[t] = t * kBktCap + bs - excl;
    }
    __syncthreads();
    for (int e = e0 + t; e < e1; e += kSCT) {
      int d = dst[e];
      int b = d >> kBktShift;
      int p = atomicAdd(&cur[b], 1);
      int slot = lofs[b] + p;
      val[slot] = ((uint32_t)src[e] << 8) | (uint32_t)(d & 255);
      addrs[slot] = segoff[b] + slot;
    }
    __syncthreads();
    for (int i = t; i < cnt; i += kSCT)
      pairs[addrs[i]] = val[i];
  } else {
    int tt = ((int)blockIdx.x - scatterBlocks) * kSCT + t;
    const int hN = kNodes * 32;          // 3,200,000 float4-quads
    if (tt < hN) {
      int n = tt >> 5;
      int c4 = (tt & 31) * 4;
      float4 v = *reinterpret_cast<const float4*>(h + (size_t)n * kDin + c4);
      ushort4 o;
      o.x = f2bf(v.x); o.y = f2bf(v.y); o.z = f2bf(v.z); o.w = f2bf(v.w);
      *reinterpret_cast<ushort4*>(A16 + (size_t)n * kK + c4) = o;
      *reinterpret_cast<uint32_t*>(H8 + (size_t)n * kDin + c4) =
          pack4_e4m3(v.x, v.y, v.z, v.w);
    } else {
      int u = tt - hN;                   // 0 .. 65535
      int j = u & 255;
      int k = u >> 8;
      float v = (k < 128) ? Ws[(size_t)k * kDhid + j] : Wn[(size_t)(k - 128) * kDhid + j];
      Wt[(size_t)j * kK + k] = f2bf(v);
    }
  }
}

// ---------------------------------------------------------------------------
// bucket_fill: one block per bucket.  LDS degree hist -> scan -> row/rend +
// csr (gapped layout, base = b*kBktCap).
// ---------------------------------------------------------------------------
__global__ void bucket_fill(const uint32_t* __restrict__ pairs, const int* __restrict__ bktCur,
                            int* __restrict__ row, int* __restrict__ rend,
                            int* __restrict__ csr) {
  __shared__ int deg[256], scn[256], cur[256];
  int b = blockIdx.x;
  int t = threadIdx.x;
  int cnt = bktCur[b];
  int e0 = b * kBktCap;
  int nb0 = b << kBktShift;
  deg[t] = 0;
  __syncthreads();
  for (int e = t; e < cnt; e += 256)
    atomicAdd(&deg[pairs[e0 + e] & 255u], 1);
  __syncthreads();
  int d = deg[t];
  scn[t] = d;
  __syncthreads();
#pragma unroll
  for (int off = 1; off < 256; off <<= 1) {
    int u = (t >= off) ? scn[t - off] : 0;
    __syncthreads();
    scn[t] += u;
    __syncthreads();
  }
  int excl = scn[t] - d;
  cur[t] = excl;
  int n = nb0 + t;
  if (n < kNodes) { row[n] = e0 + excl; rend[n] = e0 + scn[t]; }
  __syncthreads();
  for (int e = t; e < cnt; e += 256) {
    uint32_t pr = pairs[e0 + e];
    int p = atomicAdd(&cur[pr & 255u], 1);
    csr[e0 + p] = (int)(pr >> 8);
  }
}

// ---------------------------------------------------------------------------
// agg_zero: block-routed merge of gsum-replica zeroing (first zeroBlocks
// blocks; the pairs region is dead after bucket_fill) and aggregate8
// (group-per-node fp8 gather-mean, remaining 6250 blocks).  Saves one
// launch + gap vs a separate zero_gsum kernel.
// ---------------------------------------------------------------------------
__global__ void agg_zero(const uint8_t* __restrict__ H8, ushort* __restrict__ A16,
                         const int* __restrict__ row, const int* __restrict__ rend,
                         const int* __restrict__ csr,
                         float* __restrict__ gsumR, int nzero, int zeroBlocks) {
  if ((int)blockIdx.x < zeroBlocks) {
    int t = blockIdx.x * 256 + threadIdx.x;
    if (t < nzero) gsumR[t] = 0.f;
    return;
  }
  int wv = ((blockIdx.x - zeroBlocks) * 256 + threadIdx.x) >> 6;   // 25000 waves
  int lane = threadIdx.x & 63;
  int grp = lane >> 4;      // 0..3: node slot
  int sub = lane & 15;      // 0..15: 8B column chunk
  int n = wv * 4 + grp;                             // exact: 25000*4 = 100000
  int s0 = row[n], s1 = rend[n];
  float a0 = 0.f, a1 = 0.f, a2 = 0.f, a3 = 0.f, a4 = 0.f, a5 = 0.f, a6 = 0.f, a7 = 0.f;
#pragma unroll 4
  for (int i = s0; i < s1; ++i) {
    int s = csr[i];
    uint2 v = *reinterpret_cast<const uint2*>(H8 + (size_t)s * kDin + sub * 8);
    f2_t l0 = fp8x2_f32<false>(v.x), h0 = fp8x2_f32<true>(v.x);
    f2_t l1 = fp8x2_f32<false>(v.y), h1 = fp8x2_f32<true>(v.y);
    a0 += l0.x; a1 += l0.y; a2 += h0.x; a3 += h0.y;
    a4 += l1.x; a5 += l1.y; a6 += h1.x; a7 += h1.y;
  }
  float rd = 1.f / fmaxf((float)(s1 - s0), 1.f);
  uint4 o;
  o.x = (uint32_t)f2bf(a0 * rd) | ((uint32_t)f2bf(a1 * rd) << 16);
  o.y = (uint32_t)f2bf(a2 * rd) | ((uint32_t)f2bf(a3 * rd) << 16);
  o.z = (uint32_t)f2bf(a4 * rd) | ((uint32_t)f2bf(a5 * rd) << 16);
  o.w = (uint32_t)f2bf(a6 * rd) | ((uint32_t)f2bf(a7 * rd) << 16);
  *reinterpret_cast<uint4*>((char*)A16 + (size_t)n * 512 + 256 + sub * 16) = o;
}

// ---------------------------------------------------------------------------
// gemm_pool: W-stationary streaming, counted-vmcnt pipeline, reduced-atomic
// pooling (shfl across lhi groups -> 1 atomic/col; 8 gsum replicas).
// Round-12 lesson: never cap launch_bounds below (256,2) — spills.
// ---------------------------------------------------------------------------
__global__ __launch_bounds__(256, 2)
void gemm_pool(const ushort* __restrict__ A16, const ushort* __restrict__ Wt,
               const float* __restrict__ bias, const int* __restrict__ gid,
               float* __restrict__ gsumR, int replMask) {
  __shared__ ushort Abuf[2][32 * 256];   // 2 x 16 KB
  const int tid  = threadIdx.x;
  const int lane = tid & 63;
  const int wave = tid >> 6;             // col-slice: wave*64 .. +64
  const int lhi = lane >> 4;
  const int llo = lane & 15;
  float* gout = gsumR + (size_t)(blockIdx.x & replMask) * (kGraphs * kDhid);

  bf8_t bfr[4][8];
#pragma unroll
  for (int nf = 0; nf < 4; ++nf) {
    const char* wrow = (const char*)Wt + (size_t)(wave * 64 + nf * 16 + llo) * 512 + lhi * 16;
#pragma unroll
    for (int kk = 0; kk < 8; ++kk)
      bfr[nf][kk] = *reinterpret_cast<const bf8_t*>(wrow + kk * 64);
  }
  float bv[4];
#pragma unroll
  for (int nf = 0; nf < 4; ++nf) bv[nf] = bias[wave * 64 + nf * 16 + llo];

  auto stage = [&](int buf, int tile) {
#pragma unroll
    for (int i = 0; i < 4; ++i) {
      int r = i * 8 + (tid >> 5);
      int wb = (tid & 31) * 16;
      size_t gsrc = ((size_t)tile * 32 + r) * 512 + (size_t)(wb ^ ((r & 7) << 4));
      uint32_t ldst = (uint32_t)(i * 4096 + tid * 16);
      __builtin_amdgcn_global_load_lds(
          (const __attribute__((address_space(1))) uint32_t*)((const char*)A16 + gsrc),
          (__attribute__((address_space(3))) uint32_t*)((char*)&Abuf[buf][0] + ldst),
          16, 0, 0);
    }
  };

  const int t0 = blockIdx.x * kTPB;
  stage(0, t0);

  float pooled[4] = {0.f, 0.f, 0.f, 0.f};
  int cur_g = gid[t0 * 32];

  auto flushp = [&](int g) {
#pragma unroll
    for (int nf = 0; nf < 4; ++nf) {
      float v = pooled[nf];
      v += __shfl_xor(v, 16, 64);
      v += __shfl_xor(v, 32, 64);
      if (lhi == 0 && v != 0.f)
        atomicAdd(&gout[g * kDhid + wave * 64 + nf * 16 + llo], v);
      pooled[nf] = 0.f;
    }
  };

  for (int ti = 0; ti < kTPB; ++ti) {
    int tile = t0 + ti;
    if (ti + 1 < kTPB) {
      stage((ti + 1) & 1, tile + 1);
      asm volatile("s_waitcnt vmcnt(4)" ::: "memory");
    } else {
      asm volatile("s_waitcnt vmcnt(0)" ::: "memory");
    }
    __builtin_amdgcn_s_barrier();
    __builtin_amdgcn_sched_barrier(0);

    f4_t acc[2][4];
#pragma unroll
    for (int mf = 0; mf < 2; ++mf)
#pragma unroll
      for (int nf = 0; nf < 4; ++nf) acc[mf][nf] = (f4_t)0.f;
    const char* abase = (const char*)&Abuf[ti & 1][0];
    const int swz = (llo & 7) << 4;
#pragma unroll
    for (int kk = 0; kk < 8; ++kk) {
      int kb = kk * 64 + lhi * 16;
      bf8_t x0 = *reinterpret_cast<const bf8_t*>(abase + llo * 512 + (kb ^ swz));
      bf8_t x1 = *reinterpret_cast<const bf8_t*>(abase + (16 + llo) * 512 + (kb ^ swz));
#pragma unroll
      for (int nf = 0; nf < 4; ++nf) {
        acc[0][nf] = __builtin_amdgcn_mfma_f32_16x16x32_bf16(x0, bfr[nf][kk], acc[0][nf], 0, 0, 0);
        acc[1][nf] = __builtin_amdgcn_mfma_f32_16x16x32_bf16(x1, bfr[nf][kk], acc[1][nf], 0, 0, 0);
      }
    }

    int base = tile * 32;
    int gA = gid[base], gB = gid[base + 31];
    if (gA == gB) {
      if (gA != cur_g) { flushp(cur_g); cur_g = gA; }
#pragma unroll
      for (int nf = 0; nf < 4; ++nf) {
        float s = 0.f;
#pragma unroll
        for (int mf = 0; mf < 2; ++mf)
#pragma unroll
          for (int q = 0; q < 4; ++q) s += fmaxf(acc[mf][nf][q] + bv[nf], 0.f);
        pooled[nf] += s;
      }
    } else {
#pragma unroll
      for (int mf = 0; mf < 2; ++mf)
#pragma unroll
        for (int q = 0; q < 4; ++q) {
          int r = base + mf * 16 + lhi * 4 + q;
          int g = gid[r];
#pragma unroll
          for (int nf = 0; nf < 4; ++nf) {
            float v = fmaxf(acc[mf][nf][q] + bv[nf], 0.f);
            if (v != 0.f) atomicAdd(&gout[g * kDhid + wave * 64 + nf * 16 + llo], v);
          }
        }
    }
    __builtin_amdgcn_sched_barrier(0);
    __builtin_amdgcn_s_barrier();
  }
  flushp(cur_g);
}

// ---------------------------------------------------------------------------
// head: out[g] = (sum_r gsumR[r][g] / cnt[g]) @ Wp + bp.
// ---------------------------------------------------------------------------
__global__ void head_kernel(const float* __restrict__ gsumR, int nrepl,
                            const float* __restrict__ Wp,
                            const float* __restrict__ bp,
                            const int* __restrict__ gid,
                            float* __restrict__ out) {
  __shared__ float sgs[kDhid];
  int g = blockIdx.x;
  int t = threadIdx.x;
  int lo0 = 0, hi0 = kNodes;
  while (lo0 < hi0) { int m = (lo0 + hi0) >> 1; if (gid[m] < g) lo0 = m + 1; else hi0 = m; }
  int lo1 = lo0, hi1 = kNodes;
  while (lo1 < hi1) { int m = (lo1 + hi1) >> 1; if (gid[m] < g + 1) lo1 = m + 1; else hi1 = m; }
  float rc = 1.0f / fmaxf((float)(lo1 - lo0), 1.0f);
  float s = 0.f;
  for (int r = 0; r < nrepl; ++r)
    s += gsumR[(size_t)r * (kGraphs * kDhid) + g * kDhid + t];
  sgs[t] = s * rc;
  __syncthreads();
  if (t < kClasses) {
    float acc = bp[t];
    for (int k = 0; k < kDhid; ++k)
      acc += sgs[k] * Wp[k * kClasses + t];
    out[g * kClasses + t] = acc;
  }
}

// ---------------------------------------------------------------------------
extern "C" void kernel_launch(void* const* d_in, const int* in_sizes, int n_in,
                              void* d_out, int out_size, void* d_ws, size_t ws_size,
                              hipStream_t stream) {
  const float* h  = (const float*)d_in[0];
  const float* Ws = (const float*)d_in[1];
  const float* Wn = (const float*)d_in[2];
  const float* b  = (const float*)d_in[3];
  const float* Wp = (const float*)d_in[4];
  const float* bp = (const float*)d_in[5];
  const int* src  = (const int*)d_in[6];
  const int* dst  = (const int*)d_in[7];
  const int* gid  = (const int*)d_in[8];
  float* out = (float*)d_out;

  char* ws = (char*)d_ws;
  const size_t a16Off    = 0;             // 100000*256*2 = 51,200,000
  const size_t wtOff     = 51249152;      // 131,072
  const size_t csrOff    = 51380224;      // 392*5120*4 = 8,028,160
  const size_t rowOff    = 59408384;      // 400,000
  const size_t rendOff   = 59808384;      // 400,000
  const size_t gsumOff   = 60208384;      // 65,536 (small-ws single replica)
  const size_t bktCurOff = 60273920;      // 1,568
  const size_t h8Off     = 60275712;      // 12,800,000 (fp8 gather table)
  const size_t pairsOff  = 73075712;      // 8,028,160 (non-aliased, big-ws path)
  const size_t needBig   = pairsOff + 8028160;   // 81,103,872
  ushort* A16     = (ushort*)(ws + a16Off);
  ushort* Wt      = (ushort*)(ws + wtOff);
  int* csr        = (int*)(ws + csrOff);
  int* row        = (int*)(ws + rowOff);
  int* rend       = (int*)(ws + rendOff);
  int* bktCur     = (int*)(ws + bktCurOff);
  uint8_t* H8     = (uint8_t*)(ws + h8Off);
  const bool bigWs = (ws_size >= needBig);
  uint32_t* pairs = bigWs ? (uint32_t*)(ws + pairsOff) : (uint32_t*)(ws + a16Off);
  const int nrepl = bigWs ? kRepl : 1;
  float* gsumR    = bigWs ? (float*)(ws + pairsOff) : (float*)(ws + gsumOff);

  hipLaunchKernelGGL(zero_bkt, dim3((NB + 255) / 256), dim3(256), 0, stream, bktCur);

  if (bigWs) {
    hipLaunchKernelGGL(scatter_cvt, dim3(kEBlocks + kCvtBlocks), dim3(kSCT), 0, stream,
                       src, dst, bktCur, pairs, h, Ws, Wn, A16, Wt, H8, kEBlocks);
    hipLaunchKernelGGL(bucket_fill, dim3(NB), dim3(256), 0, stream,
                       pairs, bktCur, row, rend, csr);
  } else {
    hipLaunchKernelGGL(scatter_cvt, dim3(kEBlocks), dim3(kSCT), 0, stream,
                       src, dst, bktCur, pairs, h, Ws, Wn, A16, Wt, H8, kEBlocks);
    hipLaunchKernelGGL(bucket_fill, dim3(NB), dim3(256), 0, stream,
                       pairs, bktCur, row, rend, csr);
    hipLaunchKernelGGL(scatter_cvt, dim3(kCvtBlocks), dim3(kSCT), 0, stream,
                       src, dst, bktCur, pairs, h, Ws, Wn, A16, Wt, H8, 0);
  }

  // aggregate8 + gsum-replica zeroing merged (pairs region dead after fill)
  {
    int nzero = nrepl * kGraphs * kDhid;
    int zb = (nzero + 255) / 256;
    hipLaunchKernelGGL(agg_zero, dim3(zb + kAggBlocks), dim3(256), 0, stream,
                       H8, A16, row, rend, csr, gsumR, nzero, zb);
  }

  hipLaunchKernelGGL(gemm_pool, dim3(kGemmBlocks), dim3(256), 0, stream,
                     A16, Wt, b, gid, gsumR, nrepl - 1);
  hipLaunchKernelGGL(head_kernel, dim3(kGraphs), dim3(kDhid), 0, stream,
                     gsumR, nrepl, Wp, bp, gid, out);
}